// Round 1
// baseline (434.294 us; speedup 1.0000x reference)
//
#include <hip/hip_runtime.h>

#define DEVI __device__ __forceinline__

typedef __attribute__((ext_vector_type(8))) short short8;
typedef __attribute__((ext_vector_type(4))) float f32x4;

#define ATTN_SCALE 0.10206207261596575f  // 96^-0.5

DEVI unsigned short f2bf(float f){
  unsigned u = __float_as_uint(f);
  u += 0x7fff + ((u >> 16) & 1);          // RNE
  return (unsigned short)(u >> 16);
}
DEVI float bf2f(unsigned short h){ return __uint_as_float(((unsigned)h) << 16); }

DEVI void gload16(const void* g, void* l){
  __builtin_amdgcn_global_load_lds((const __attribute__((address_space(1))) void*)g,
                                   (__attribute__((address_space(3))) void*)l, 16, 0, 0);
}

DEVI f32x4 mfma16(short8 a, short8 b, f32x4 c){
  return __builtin_amdgcn_mfma_f32_16x16x32_bf16(a, b, c, 0, 0, 0);
}

// ---------------- K1: f32 -> bf16 convert (hidden), convert+transpose (qkv_w) ---
__global__ __launch_bounds__(256) void k_convert(const float4* __restrict__ hs4,
    const float* __restrict__ w, unsigned short* __restrict__ hsb,
    unsigned short* __restrict__ wt){
  const int stride = gridDim.x * 256;
  const int t0 = blockIdx.x * 256 + threadIdx.x;
  const int n4 = (50176 * 192) / 4;
  for (int i = t0; i < n4; i += stride){
    float4 v = hs4[i];
    uint2 p;
    p.x = (unsigned)f2bf(v.x) | ((unsigned)f2bf(v.y) << 16);
    p.y = (unsigned)f2bf(v.z) | ((unsigned)f2bf(v.w) << 16);
    ((uint2*)hsb)[i] = p;
  }
  for (int i = t0; i < 192 * 1152; i += stride){
    int k = i / 1152, n = i - k * 1152;
    wt[n * 192 + k] = f2bf(w[i]);
  }
}

// ---------------- K2: QKV GEMM  C[50176,1152] = A[50176,192] * W[192,1152] + b --
__global__ __launch_bounds__(256) void k_gemm(const unsigned short* __restrict__ A,
    const unsigned short* __restrict__ Bt,   // [1152][192] (pre-transposed, K-major)
    const float* __restrict__ bias, unsigned short* __restrict__ C){
  __shared__ unsigned short sA[128 * 64];
  __shared__ unsigned short sB[128 * 64];
  const int bn = blockIdx.x % 9, bm = blockIdx.x / 9;
  const int tid = threadIdx.x, w = tid >> 6, l = tid & 63;
  const int wr = (w >> 1) * 64, wc = (w & 1) * 64;
  const int l15 = l & 15, l4 = l >> 4;
  const f32x4 z4 = {0.f, 0.f, 0.f, 0.f};
  f32x4 acc[4][4];
#pragma unroll
  for (int i = 0; i < 4; ++i)
#pragma unroll
    for (int j = 0; j < 4; ++j) acc[i][j] = z4;

  for (int kk = 0; kk < 3; ++kk){
    const int k0 = kk * 64;
#pragma unroll
    for (int i = 0; i < 4; ++i){
      const int ib = (w * 4 + i) << 10;
      const int Lb = ib + (l << 4);
      const int r  = Lb >> 7;                       // LDS row (128B rows)
      const int g  = ((Lb >> 4) & 7) ^ (r & 7);     // pre-swizzled source granule
      gload16((const char*)A  + (size_t)(bm * 128 + r) * 384 + k0 * 2 + g * 16, (char*)sA + ib);
      gload16((const char*)Bt + (size_t)(bn * 128 + r) * 384 + k0 * 2 + g * 16, (char*)sB + ib);
    }
    __syncthreads();
#pragma unroll
    for (int ks = 0; ks < 2; ++ks){
      short8 av[4], bv[4];
#pragma unroll
      for (int mf = 0; mf < 4; ++mf){
        const int r = wr + mf * 16 + l15;
        const int slot = (ks * 4 + l4) ^ (r & 7);
        av[mf] = *(const short8*)(sA + r * 64 + slot * 8);
      }
#pragma unroll
      for (int nf = 0; nf < 4; ++nf){
        const int r = wc + nf * 16 + l15;
        const int slot = (ks * 4 + l4) ^ (r & 7);
        bv[nf] = *(const short8*)(sB + r * 64 + slot * 8);
      }
#pragma unroll
      for (int mf = 0; mf < 4; ++mf)
#pragma unroll
        for (int nf = 0; nf < 4; ++nf)
          acc[mf][nf] = mfma16(av[mf], bv[nf], acc[mf][nf]);
    }
    __syncthreads();
  }
#pragma unroll
  for (int nf = 0; nf < 4; ++nf){
    const int col = bn * 128 + wc + nf * 16 + l15;
    const float bv = bias[col];
#pragma unroll
    for (int mf = 0; mf < 4; ++mf)
#pragma unroll
      for (int reg = 0; reg < 4; ++reg){
        const int row = bm * 128 + wr + mf * 16 + l4 * 4 + reg;
        C[(size_t)row * 1152 + col] = f2bf(acc[mf][nf][reg] + bv);
      }
  }
}

// ---------------- K3: depthwise 3x3 s2 pool + LayerNorm ------------------------
__global__ __launch_bounds__(256) void k_pool_ln(const unsigned short* __restrict__ qkv,
    const float* __restrict__ wq, const float* __restrict__ wk, const float* __restrict__ wv,
    const float* __restrict__ gq, const float* __restrict__ bq,
    const float* __restrict__ gk, const float* __restrict__ bk,
    const float* __restrict__ gv, const float* __restrict__ bv,
    unsigned short* __restrict__ qp, unsigned short* __restrict__ kp,
    unsigned short* __restrict__ vpt, float* __restrict__ qpf){
  __shared__ float sw[864];
  __shared__ float sg[96], sb[96];
  __shared__ float sbuf[28 * 96];
  const int bid = blockIdx.x;
  const int oy = bid % 28, h = (bid / 28) & 3, b = (bid / 112) & 15, which = bid / 1792;
  const float* wsel = which == 0 ? wq : (which == 1 ? wk : wv);
  const float* gsel = which == 0 ? gq : (which == 1 ? gk : gv);
  const float* bsel = which == 0 ? bq : (which == 1 ? bk : bv);
  const int tid = threadIdx.x;
  for (int i = tid; i < 864; i += 256) sw[i] = wsel[i];
  if (tid < 96){ sg[tid] = gsel[tid]; sb[tid] = bsel[tid]; }
  __syncthreads();
  const int colbase = which * 384 + h * 96;
  for (int item = tid; item < 2688; item += 256){
    const int ox = item / 96, d = item - ox * 96;
    float acc = 0.f;
#pragma unroll
    for (int ky = 0; ky < 3; ++ky){
      const int iy = oy * 2 + ky - 1;
      if ((unsigned)iy >= 56u) continue;
      const unsigned short* rowp = qkv + (size_t)(b * 3136 + iy * 56) * 1152 + colbase + d;
#pragma unroll
      for (int kx = 0; kx < 3; ++kx){
        const int ix = ox * 2 + kx - 1;
        if ((unsigned)ix >= 56u) continue;
        acc += bf2f(rowp[(size_t)ix * 1152]) * sw[d * 9 + ky * 3 + kx];
      }
    }
    sbuf[ox * 96 + d] = acc;
  }
  __syncthreads();
  const int wv_ = tid >> 6, l = tid & 63;
  const size_t bh = (size_t)(b * 4 + h);
  for (int oxi = 0; oxi < 7; ++oxi){
    const int ox = wv_ * 7 + oxi;
    const float x1 = sbuf[ox * 96 + l];
    const float x2 = (l < 32) ? sbuf[ox * 96 + 64 + l] : 0.f;
    float s = x1 + x2, ss = x1 * x1 + x2 * x2;
#pragma unroll
    for (int d = 1; d < 64; d <<= 1){ s += __shfl_xor(s, d); ss += __shfl_xor(ss, d); }
    const float mean = s * (1.f / 96.f);
    const float var  = ss * (1.f / 96.f) - mean * mean;
    const float rstd = rsqrtf(var + 1e-6f);
    const int n = oy * 28 + ox;
    {
      const float y = (x1 - mean) * rstd * sg[l] + sb[l];
      if (which == 0){ const size_t idx = (bh * 784 + n) * 96 + l; qp[idx] = f2bf(y); qpf[idx] = y; }
      else if (which == 1){ kp[(bh * 784 + n) * 96 + l] = f2bf(y); }
      else { vpt[(bh * 96 + l) * 784 + n] = f2bf(y); }
    }
    if (l < 32){
      const int d = 64 + l;
      const float y = (x2 - mean) * rstd * sg[d] + sb[d];
      if (which == 0){ const size_t idx = (bh * 784 + n) * 96 + d; qp[idx] = f2bf(y); qpf[idx] = y; }
      else if (which == 1){ kp[(bh * 784 + n) * 96 + d] = f2bf(y); }
      else { vpt[(bh * 96 + d) * 784 + n] = f2bf(y); }
    }
  }
}

// ---------------- K4: fused attention (flash-style, rel-pos, residual) ---------
__global__ __launch_bounds__(256) void k_attn(
    const unsigned short* __restrict__ qp, const unsigned short* __restrict__ kp,
    const unsigned short* __restrict__ vpt, const float* __restrict__ qpf,
    const float* __restrict__ relh, const float* __restrict__ relw,
    float* __restrict__ out){
  __shared__ unsigned short sQ[64 * 128];
  __shared__ unsigned short sK[64 * 128];
  __shared__ unsigned short sV[96 * 64];    // V^T tile: [d][key]
  __shared__ unsigned short sP[64 * 64];
  __shared__ float sEh[64 * 28];
  __shared__ float sEw[64 * 28];
  const int qt = blockIdx.x % 13, bh = blockIdx.x / 13;
  const int b = bh >> 2, h = bh & 3;
  const int tid = threadIdx.x, w = tid >> 6, l = tid & 63;
  const int l15 = l & 15, l4 = l >> 4;
  const size_t base = (size_t)bh * 784 * 96;
  const f32x4 z4 = {0.f, 0.f, 0.f, 0.f};

  // stage Q (pre-swizzled source; rows padded to 128 elems, pad slots get dummy data)
#pragma unroll
  for (int i = 0; i < 4; ++i){
    const int ib = (w * 4 + i) << 10;
    const int Lb = ib + (l << 4);
    const int r = Lb >> 8;                         // 256B rows
    const int g = ((Lb >> 4) & 15) ^ (r & 7);
    int qr = qt * 64 + r; if (qr > 783) qr = 783;
    const size_t gb = (base + (size_t)qr * 96) * 2 + (g < 12 ? g * 16 : 0);
    gload16((const char*)qp + gb, (char*)sQ + ib);
  }
  // Eh/Ew tables: dot(q_row, rel_h[h-kh+27]) / dot(q_row, rel_w[w-kw+27])
  for (int item = tid; item < 64 * 56; item += 256){
    const int r = item & 63, e = item >> 6;
    int qr = qt * 64 + r; if (qr > 783) qr = 783;
    const int hh = qr / 28, ww = qr - hh * 28;
    const float* qv = qpf + base + (size_t)qr * 96;
    const float* rv = (e < 28) ? (relh + (hh - e + 27) * 96)
                               : (relw + (ww - (e - 28) + 27) * 96);
    float acc = 0.f;
#pragma unroll
    for (int d = 0; d < 96; d += 4){
      const float4 a = *(const float4*)(qv + d);
      const float4 c = *(const float4*)(rv + d);
      acc += a.x * c.x + a.y * c.y + a.z * c.z + a.w * c.w;
    }
    if (e < 28) sEh[r * 28 + e] = acc; else sEw[r * 28 + e - 28] = acc;
  }
  float m_reg[4], l_reg[4];
#pragma unroll
  for (int i = 0; i < 4; ++i){ m_reg[i] = -1e30f; l_reg[i] = 0.f; }
  f32x4 acc_o[6];
#pragma unroll
  for (int i = 0; i < 6; ++i) acc_o[i] = z4;
  __syncthreads();

  for (int kt = 0; kt < 13; ++kt){
    // stage K tile
#pragma unroll
    for (int i = 0; i < 4; ++i){
      const int ib = (w * 4 + i) << 10;
      const int Lb = ib + (l << 4);
      const int r = Lb >> 8;
      const int g = ((Lb >> 4) & 15) ^ (r & 7);
      int kr = kt * 64 + r; if (kr > 783) kr = 783;
      const size_t gb = (base + (size_t)kr * 96) * 2 + (g < 12 ? g * 16 : 0);
      gload16((const char*)kp + gb, (char*)sK + ib);
    }
    // stage V^T tile
#pragma unroll
    for (int i = 0; i < 3; ++i){
      const int ib = (w * 3 + i) << 10;
      const int Lb = ib + (l << 4);
      const int r = Lb >> 7;                       // d row (128B rows)
      const int g = ((Lb >> 4) & 7) ^ (r & 7);
      int koff = kt * 64 + g * 8; if (koff > 776) koff = 0;   // masked later via P=0
      gload16((const char*)vpt + ((size_t)(bh * 96 + r) * 784 + koff) * 2, (char*)sV + ib);
    }
    __syncthreads();

    // S = Q K^T  (wave w owns rows 16w..16w+15)
    f32x4 sfr[4];
#pragma unroll
    for (int i = 0; i < 4; ++i) sfr[i] = z4;
#pragma unroll
    for (int ks = 0; ks < 3; ++ks){
      const int ra = w * 16 + l15;
      const int sa = (ks * 4 + l4) ^ (ra & 7);
      const short8 a = *(const short8*)(sQ + ra * 128 + sa * 8);
#pragma unroll
      for (int nf = 0; nf < 4; ++nf){
        const int rb = nf * 16 + l15;
        const int sb2 = (ks * 4 + l4) ^ (rb & 7);
        const short8 bb = *(const short8*)(sK + rb * 128 + sb2 * 8);
        sfr[nf] = mfma16(a, bb, sfr[nf]);
      }
    }
    // online softmax in fragment layout (row = w*16 + 4*(l>>4) + reg, col = l&15)
    float pvv[4][4];
    float rmax[4] = {-1e30f, -1e30f, -1e30f, -1e30f};
    const int rbase = w * 16 + l4 * 4;
#pragma unroll
    for (int nf = 0; nf < 4; ++nf){
      const int kidx = kt * 64 + nf * 16 + l15;
      const bool valid = kidx < 784;
      const int kc = valid ? kidx : 0;
      const int kh = (kc * 2341) >> 16;            // /28
      const int kw2 = kc - kh * 28;
#pragma unroll
      for (int reg = 0; reg < 4; ++reg){
        const int rl = rbase + reg;
        const float sv = valid ? (sfr[nf][reg] * ATTN_SCALE + sEh[rl * 28 + kh] + sEw[rl * 28 + kw2])
                               : -1e30f;
        pvv[nf][reg] = sv;
        rmax[reg] = fmaxf(rmax[reg], sv);
      }
    }
#pragma unroll
    for (int s = 1; s < 16; s <<= 1)
#pragma unroll
      for (int reg = 0; reg < 4; ++reg)
        rmax[reg] = fmaxf(rmax[reg], __shfl_xor(rmax[reg], s));
    float alpha[4], rsum[4];
#pragma unroll
    for (int reg = 0; reg < 4; ++reg){
      const float mn = fmaxf(m_reg[reg], rmax[reg]);
      alpha[reg] = __expf(m_reg[reg] - mn);
      m_reg[reg] = mn;
      rsum[reg] = 0.f;
    }
#pragma unroll
    for (int nf = 0; nf < 4; ++nf)
#pragma unroll
      for (int reg = 0; reg < 4; ++reg){
        const float p = __expf(pvv[nf][reg] - m_reg[reg]);
        pvv[nf][reg] = p;
        rsum[reg] += p;
      }
#pragma unroll
    for (int s = 1; s < 16; s <<= 1)
#pragma unroll
      for (int reg = 0; reg < 4; ++reg)
        rsum[reg] += __shfl_xor(rsum[reg], s);
#pragma unroll
    for (int reg = 0; reg < 4; ++reg)
      l_reg[reg] = l_reg[reg] * alpha[reg] + rsum[reg];
    // write P (bf16, XOR-swizzled rows of 64)
#pragma unroll
    for (int nf = 0; nf < 4; ++nf)
#pragma unroll
      for (int reg = 0; reg < 4; ++reg){
        const int rl = rbase + reg;
        const int c = nf * 16 + l15;
        const int slot = (c >> 3) ^ (rl & 7);
        sP[rl * 64 + slot * 8 + (c & 7)] = f2bf(pvv[nf][reg]);
      }
    // rescale O
#pragma unroll
    for (int i = 0; i < 6; ++i)
#pragma unroll
      for (int reg = 0; reg < 4; ++reg)
        acc_o[i][reg] *= alpha[reg];
    __syncthreads();
    // O += P V
#pragma unroll
    for (int ks = 0; ks < 2; ++ks){
      const int ra = w * 16 + l15;
      const int sa = (ks * 4 + l4) ^ (ra & 7);
      const short8 a = *(const short8*)(sP + ra * 64 + sa * 8);
#pragma unroll
      for (int nf = 0; nf < 6; ++nf){
        const int rv_ = nf * 16 + l15;
        const int sv2 = (ks * 4 + l4) ^ (rv_ & 7);
        const short8 bb = *(const short8*)(sV + rv_ * 64 + sv2 * 8);
        acc_o[nf] = mfma16(a, bb, acc_o[nf]);
      }
    }
    __syncthreads();
  }
  // epilogue: normalize, add residual q, write [B,784,384]
#pragma unroll
  for (int nf = 0; nf < 6; ++nf){
    const int d = nf * 16 + l15;
#pragma unroll
    for (int reg = 0; reg < 4; ++reg){
      const int rl = w * 16 + l4 * 4 + reg;
      const int qr = qt * 64 + rl;
      if (qr < 784){
        const float v = acc_o[nf][reg] / l_reg[reg] + qpf[base + (size_t)qr * 96 + d];
        out[((size_t)b * 784 + qr) * 384 + h * 96 + d] = v;
      }
    }
  }
}

// ---------------- launcher -----------------------------------------------------
extern "C" void kernel_launch(void* const* d_in, const int* in_sizes, int n_in,
                              void* d_out, int out_size, void* d_ws, size_t ws_size,
                              hipStream_t stream){
  const float* hs  = (const float*)d_in[0];
  const float* qw  = (const float*)d_in[1];
  const float* qb  = (const float*)d_in[2];
  const float* pwq = (const float*)d_in[3];
  const float* pwk = (const float*)d_in[4];
  const float* pwv = (const float*)d_in[5];
  const float* gq  = (const float*)d_in[6];
  const float* bq  = (const float*)d_in[7];
  const float* gk  = (const float*)d_in[8];
  const float* bk  = (const float*)d_in[9];
  const float* gv  = (const float*)d_in[10];
  const float* bv  = (const float*)d_in[11];
  const float* rh  = (const float*)d_in[12];
  const float* rw  = (const float*)d_in[13];
  float* out = (float*)d_out;

  char* ws = (char*)d_ws;
  size_t off = 0;
  auto take = [&](size_t n)->char*{ char* p = ws + off; off += (n + 255) & ~(size_t)255; return p; };
  unsigned short* hsb = (unsigned short*)take((size_t)50176 * 192 * 2);
  unsigned short* wtb = (unsigned short*)take((size_t)1152 * 192 * 2);
  unsigned short* qkv = (unsigned short*)take((size_t)50176 * 1152 * 2);
  unsigned short* qpb = (unsigned short*)take((size_t)64 * 784 * 96 * 2);
  unsigned short* kpb = (unsigned short*)take((size_t)64 * 784 * 96 * 2);
  unsigned short* vpt = (unsigned short*)take((size_t)64 * 784 * 96 * 2);
  float* qpf          = (float*)take((size_t)64 * 784 * 96 * 4);

  hipLaunchKernelGGL(k_convert, dim3(1024), dim3(256), 0, stream,
                     (const float4*)hs, qw, hsb, wtb);
  hipLaunchKernelGGL(k_gemm, dim3(392 * 9), dim3(256), 0, stream, hsb, wtb, qb, qkv);
  hipLaunchKernelGGL(k_pool_ln, dim3(5376), dim3(256), 0, stream, qkv,
                     pwq, pwk, pwv, gq, bq, gk, bk, gv, bv, qpb, kpb, vpt, qpf);
  hipLaunchKernelGGL(k_attn, dim3(64 * 13), dim3(256), 0, stream,
                     qpb, kpb, vpt, qpf, rh, rw, out);
}